// Round 1
// baseline (357.205 us; speedup 1.0000x reference)
//
#include <hip/hip_runtime.h>

#define EPS 1e-5f

constexpr int F    = 256;        // features
constexpr int F4   = 64;         // float4 per row
constexpr int ROWS = 32 * 4096;  // 131072 rows
constexpr int RG   = ROWS / 4;   // 32768 row-groups (4 rows / block-iter)

// ---------------------------------------------------------------------------
// Pass 1: per-feature partial sums over masked rows.
// Layout: wave w (of 4) handles row rg*4+w; lane l handles float4 chunk l
// (features 4l..4l+3). Mask branch is wave-uniform -> no divergence.
// Partials stored column-major pS[f * nblk + b] so finalize reads contiguous.
// ---------------------------------------------------------------------------
__global__ void __launch_bounds__(256) reduce_kernel(
    const float4* __restrict__ x4, const int* __restrict__ mask,
    float* __restrict__ pS1, float* __restrict__ pS2,
    float* __restrict__ pCnt, int nblk)
{
    const int lane = threadIdx.x & 63;
    const int wv   = threadIdx.x >> 6;

    float4 s1 = {0.f, 0.f, 0.f, 0.f};
    float4 s2 = {0.f, 0.f, 0.f, 0.f};
    float  cnt = 0.f;

    for (int rg = blockIdx.x; rg < RG; rg += nblk) {
        const int row = rg * 4 + wv;
        const int m   = mask[row];           // same addr across wave: broadcast
        if (m > 0) {
            const float4 v = x4[(size_t)row * F4 + lane];
            s1.x += v.x; s1.y += v.y; s1.z += v.z; s1.w += v.w;
            s2.x = fmaf(v.x, v.x, s2.x);
            s2.y = fmaf(v.y, v.y, s2.y);
            s2.z = fmaf(v.z, v.z, s2.z);
            s2.w = fmaf(v.w, v.w, s2.w);
            cnt += 1.f;
        }
    }

    __shared__ float4 sh1[256];
    __shared__ float4 sh2[256];
    __shared__ float  shc[4];
    sh1[threadIdx.x] = s1;
    sh2[threadIdx.x] = s2;
    if (lane == 0) shc[wv] = cnt;            // cnt is wave-uniform
    __syncthreads();

    if (wv == 0) {
        float4 a = sh1[lane];
        float4 b = sh2[lane];
        #pragma unroll
        for (int w = 1; w < 4; ++w) {
            const float4 c = sh1[w * 64 + lane];
            const float4 d = sh2[w * 64 + lane];
            a.x += c.x; a.y += c.y; a.z += c.z; a.w += c.w;
            b.x += d.x; b.y += d.y; b.z += d.z; b.w += d.w;
        }
        const int f0 = lane * 4;
        const int blk = blockIdx.x;
        pS1[(size_t)(f0 + 0) * nblk + blk] = a.x;
        pS1[(size_t)(f0 + 1) * nblk + blk] = a.y;
        pS1[(size_t)(f0 + 2) * nblk + blk] = a.z;
        pS1[(size_t)(f0 + 3) * nblk + blk] = a.w;
        pS2[(size_t)(f0 + 0) * nblk + blk] = b.x;
        pS2[(size_t)(f0 + 1) * nblk + blk] = b.y;
        pS2[(size_t)(f0 + 2) * nblk + blk] = b.z;
        pS2[(size_t)(f0 + 3) * nblk + blk] = b.w;
        if (lane == 0)
            pCnt[blk] = shc[0] + shc[1] + shc[2] + shc[3];
    }
}

// ---------------------------------------------------------------------------
// Pass 2: fold partials -> scale/shift per feature.
// ---------------------------------------------------------------------------
__global__ void __launch_bounds__(64) finalize_kernel(
    const float* __restrict__ pS1, const float* __restrict__ pS2,
    const float* __restrict__ pCnt,
    const float* __restrict__ gamma, const float* __restrict__ beta,
    float* __restrict__ scale, float* __restrict__ shift, int nblk)
{
    const int f = blockIdx.x * 64 + threadIdx.x;   // 0..255

    float cnt = 0.f;
    for (int b = 0; b < nblk; ++b) cnt += pCnt[b]; // broadcast reads, tiny

    float s1 = 0.f, s2 = 0.f;
    const float* c1 = pS1 + (size_t)f * nblk;
    const float* c2 = pS2 + (size_t)f * nblk;
    for (int b = 0; b < nblk; ++b) { s1 += c1[b]; s2 += c2[b]; }

    const float inv_cnt = 1.f / cnt;
    const float mean = s1 * inv_cnt;
    const float var  = fmaf(-mean, mean, s2 * inv_cnt);  // E[x^2]-mean^2
    const float inv  = rsqrtf(var + EPS);
    const float g    = gamma[f] * inv;
    scale[f] = g;
    shift[f] = fmaf(-mean, g, beta[f]);
}

// ---------------------------------------------------------------------------
// Pass 3: out = mask ? x*scale + shift : x   (wave-per-row, float4)
// ---------------------------------------------------------------------------
__global__ void __launch_bounds__(256) norm_kernel(
    const float4* __restrict__ x4, const int* __restrict__ mask,
    const float4* __restrict__ scale4, const float4* __restrict__ shift4,
    float4* __restrict__ out4)
{
    const int lane = threadIdx.x & 63;
    const int wv   = threadIdx.x >> 6;
    const float4 sc = scale4[lane];
    const float4 sh = shift4[lane];

    for (int rg = blockIdx.x; rg < RG; rg += gridDim.x) {
        const int row = rg * 4 + wv;
        const int m   = mask[row];
        const size_t idx = (size_t)row * F4 + lane;
        const float4 v = x4[idx];
        float4 o;
        if (m > 0) {
            o.x = fmaf(v.x, sc.x, sh.x);
            o.y = fmaf(v.y, sc.y, sh.y);
            o.z = fmaf(v.z, sc.z, sh.z);
            o.w = fmaf(v.w, sc.w, sh.w);
        } else {
            o = v;
        }
        out4[idx] = o;
    }
}

// ---------------------------------------------------------------------------
extern "C" void kernel_launch(void* const* d_in, const int* in_sizes, int n_in,
                              void* d_out, int out_size, void* d_ws, size_t ws_size,
                              hipStream_t stream)
{
    const float* x     = (const float*)d_in[0];
    const int*   mask  = (const int*)d_in[1];
    const float* gamma = (const float*)d_in[2];
    const float* beta  = (const float*)d_in[3];
    float* out = (float*)d_out;
    float* ws  = (float*)d_ws;

    // ws layout: pS1[F*nblk] | pS2[F*nblk] | pCnt[nblk] | scale[256] | shift[256]
    int nblk = 512;
    while (nblk > 4 &&
           ((size_t)nblk * F * 2 + nblk + 512) * sizeof(float) > ws_size)
        nblk >>= 1;

    float* pS1   = ws;
    float* pS2   = pS1 + (size_t)F * nblk;
    float* pCnt  = pS2 + (size_t)F * nblk;
    float* scale = pCnt + nblk;
    float* shift = scale + F;

    reduce_kernel<<<nblk, 256, 0, stream>>>(
        (const float4*)x, mask, pS1, pS2, pCnt, nblk);
    finalize_kernel<<<4, 64, 0, stream>>>(
        pS1, pS2, pCnt, gamma, beta, scale, shift, nblk);
    norm_kernel<<<2048, 256, 0, stream>>>(
        (const float4*)x, mask, (const float4*)scale, (const float4*)shift,
        (float4*)out);
}

// Round 2
// 261.310 us; speedup vs baseline: 1.3670x; 1.3670x over previous
//
#include <hip/hip_runtime.h>

#define EPS 1e-5f

constexpr int F    = 256;        // features
constexpr int F4   = 64;         // float4 per row
constexpr int ROWS = 32 * 4096;  // 131072 rows
constexpr int NG   = ROWS / 16;  // 8192 groups of 16 rows (4 waves x 4 rows)

// ---------------------------------------------------------------------------
// Pass 1: per-feature partial sums over masked rows.
// Each wave handles 4 CONSECUTIVE rows per iteration: one int4 mask load,
// then up to 4 independent float4 x-loads in flight. Mask branches are
// wave-uniform -> no divergence. Partials column-major pS[f*nblk + b].
// ---------------------------------------------------------------------------
__global__ void __launch_bounds__(256) reduce_kernel(
    const float4* __restrict__ x4, const int4* __restrict__ mask4,
    float* __restrict__ pS1, float* __restrict__ pS2,
    float* __restrict__ pCnt, int nblk)
{
    const int lane = threadIdx.x & 63;
    const int wv   = threadIdx.x >> 6;

    float4 s1 = {0.f, 0.f, 0.f, 0.f};
    float4 s2 = {0.f, 0.f, 0.f, 0.f};
    float  cnt = 0.f;

    for (int g = blockIdx.x; g < NG; g += nblk) {
        const int row0 = g * 16 + wv * 4;
        const int4 m = mask4[row0 >> 2];                 // wave-uniform 16B load
        const float4* p = x4 + (size_t)row0 * F4 + lane;
        if (m.x > 0) { const float4 v = p[0];
            s1.x += v.x; s1.y += v.y; s1.z += v.z; s1.w += v.w;
            s2.x = fmaf(v.x,v.x,s2.x); s2.y = fmaf(v.y,v.y,s2.y);
            s2.z = fmaf(v.z,v.z,s2.z); s2.w = fmaf(v.w,v.w,s2.w); cnt += 1.f; }
        if (m.y > 0) { const float4 v = p[F4];
            s1.x += v.x; s1.y += v.y; s1.z += v.z; s1.w += v.w;
            s2.x = fmaf(v.x,v.x,s2.x); s2.y = fmaf(v.y,v.y,s2.y);
            s2.z = fmaf(v.z,v.z,s2.z); s2.w = fmaf(v.w,v.w,s2.w); cnt += 1.f; }
        if (m.z > 0) { const float4 v = p[2 * F4];
            s1.x += v.x; s1.y += v.y; s1.z += v.z; s1.w += v.w;
            s2.x = fmaf(v.x,v.x,s2.x); s2.y = fmaf(v.y,v.y,s2.y);
            s2.z = fmaf(v.z,v.z,s2.z); s2.w = fmaf(v.w,v.w,s2.w); cnt += 1.f; }
        if (m.w > 0) { const float4 v = p[3 * F4];
            s1.x += v.x; s1.y += v.y; s1.z += v.z; s1.w += v.w;
            s2.x = fmaf(v.x,v.x,s2.x); s2.y = fmaf(v.y,v.y,s2.y);
            s2.z = fmaf(v.z,v.z,s2.z); s2.w = fmaf(v.w,v.w,s2.w); cnt += 1.f; }
    }

    __shared__ float4 sh1[256];
    __shared__ float4 sh2[256];
    __shared__ float  shc[4];
    sh1[threadIdx.x] = s1;
    sh2[threadIdx.x] = s2;
    if (lane == 0) shc[wv] = cnt;            // cnt is wave-uniform
    __syncthreads();

    if (wv == 0) {
        float4 a = sh1[lane];
        float4 b = sh2[lane];
        #pragma unroll
        for (int w = 1; w < 4; ++w) {
            const float4 c = sh1[w * 64 + lane];
            const float4 d = sh2[w * 64 + lane];
            a.x += c.x; a.y += c.y; a.z += c.z; a.w += c.w;
            b.x += d.x; b.y += d.y; b.z += d.z; b.w += d.w;
        }
        const int f0  = lane * 4;
        const int blk = blockIdx.x;
        pS1[(size_t)(f0 + 0) * nblk + blk] = a.x;
        pS1[(size_t)(f0 + 1) * nblk + blk] = a.y;
        pS1[(size_t)(f0 + 2) * nblk + blk] = a.z;
        pS1[(size_t)(f0 + 3) * nblk + blk] = a.w;
        pS2[(size_t)(f0 + 0) * nblk + blk] = b.x;
        pS2[(size_t)(f0 + 1) * nblk + blk] = b.y;
        pS2[(size_t)(f0 + 2) * nblk + blk] = b.z;
        pS2[(size_t)(f0 + 3) * nblk + blk] = b.w;
        if (lane == 0)
            pCnt[blk] = shc[0] + shc[1] + shc[2] + shc[3];
    }
}

// ---------------------------------------------------------------------------
// Pass 2: fold partials -> scale/shift. One block per feature, 64 threads
// strided over the column, wave shuffle-reduce. Latency-parallel.
// ---------------------------------------------------------------------------
__global__ void __launch_bounds__(64) finalize_kernel(
    const float* __restrict__ pS1, const float* __restrict__ pS2,
    const float* __restrict__ pCnt,
    const float* __restrict__ gamma, const float* __restrict__ beta,
    float* __restrict__ scale, float* __restrict__ shift, int nblk)
{
    const int f = blockIdx.x;
    const int t = threadIdx.x;

    const float* c1 = pS1 + (size_t)f * nblk;
    const float* c2 = pS2 + (size_t)f * nblk;

    float s1 = 0.f, s2 = 0.f, c = 0.f;
    for (int b = t; b < nblk; b += 64) {
        s1 += c1[b];
        s2 += c2[b];
        c  += pCnt[b];
    }
    #pragma unroll
    for (int off = 32; off > 0; off >>= 1) {
        s1 += __shfl_down(s1, off);
        s2 += __shfl_down(s2, off);
        c  += __shfl_down(c,  off);
    }
    if (t == 0) {
        const float inv_cnt = 1.f / c;
        const float mean = s1 * inv_cnt;
        const float var  = fmaf(-mean, mean, s2 * inv_cnt);
        const float inv  = rsqrtf(var + EPS);
        const float g    = gamma[f] * inv;
        scale[f] = g;
        shift[f] = fmaf(-mean, g, beta[f]);
    }
}

// ---------------------------------------------------------------------------
// Pass 3: out = mask ? x*scale + shift : x
// Branchless: 4 consecutive rows per wave, all loads/stores unconditional
// (4 in flight), per-element select via cndmask.
// ---------------------------------------------------------------------------
__device__ __forceinline__ float4 sel4(int m, const float4 v,
                                       const float4 sc, const float4 sh)
{
    float4 o;
    o.x = (m > 0) ? fmaf(v.x, sc.x, sh.x) : v.x;
    o.y = (m > 0) ? fmaf(v.y, sc.y, sh.y) : v.y;
    o.z = (m > 0) ? fmaf(v.z, sc.z, sh.z) : v.z;
    o.w = (m > 0) ? fmaf(v.w, sc.w, sh.w) : v.w;
    return o;
}

__global__ void __launch_bounds__(256) norm_kernel(
    const float4* __restrict__ x4, const int4* __restrict__ mask4,
    const float4* __restrict__ scale4, const float4* __restrict__ shift4,
    float4* __restrict__ out4)
{
    const int lane = threadIdx.x & 63;
    const int wv   = threadIdx.x >> 6;
    const float4 sc = scale4[lane];
    const float4 sh = shift4[lane];

    for (int g = blockIdx.x; g < NG; g += gridDim.x) {
        const int row0 = g * 16 + wv * 4;
        const int4 m = mask4[row0 >> 2];
        const size_t base = (size_t)row0 * F4 + lane;
        const float4 v0 = x4[base];
        const float4 v1 = x4[base + F4];
        const float4 v2 = x4[base + 2 * F4];
        const float4 v3 = x4[base + 3 * F4];
        out4[base]          = sel4(m.x, v0, sc, sh);
        out4[base + F4]     = sel4(m.y, v1, sc, sh);
        out4[base + 2 * F4] = sel4(m.z, v2, sc, sh);
        out4[base + 3 * F4] = sel4(m.w, v3, sc, sh);
    }
}

// ---------------------------------------------------------------------------
extern "C" void kernel_launch(void* const* d_in, const int* in_sizes, int n_in,
                              void* d_out, int out_size, void* d_ws, size_t ws_size,
                              hipStream_t stream)
{
    const float* x     = (const float*)d_in[0];
    const int*   mask  = (const int*)d_in[1];
    const float* gamma = (const float*)d_in[2];
    const float* beta  = (const float*)d_in[3];
    float* out = (float*)d_out;
    float* ws  = (float*)d_ws;

    // ws layout: pS1[F*nblk] | pS2[F*nblk] | pCnt[nblk] | scale[256] | shift[256]
    int nblk = 512;
    while (nblk > 4 &&
           ((size_t)nblk * F * 2 + nblk + 512) * sizeof(float) > ws_size)
        nblk >>= 1;

    float* pS1   = ws;
    float* pS2   = pS1 + (size_t)F * nblk;
    float* pCnt  = pS2 + (size_t)F * nblk;
    float* scale = pCnt + nblk;
    float* shift = scale + F;

    reduce_kernel<<<nblk, 256, 0, stream>>>(
        (const float4*)x, (const int4*)mask, pS1, pS2, pCnt, nblk);
    finalize_kernel<<<F, 64, 0, stream>>>(
        pS1, pS2, pCnt, gamma, beta, scale, shift, nblk);
    norm_kernel<<<2048, 256, 0, stream>>>(
        (const float4*)x, (const int4*)mask, (const float4*)scale,
        (const float4*)shift, (float4*)out);
}